// Round 10
// baseline (184.727 us; speedup 1.0000x reference)
//
#include <hip/hip_runtime.h>
#include <hip/hip_fp16.h>

#define D 64
#define BETA 0.9f
#define ALPHA 0.1f
#define CB_SHIFT 10
#define CB_ROWS 1024          // rows per coarse bucket
#define CAP_SHIFT 14
#define CAP (1 << CAP_SHIFT)  // edge slots per bucket (16384 >> ~10.2K mean)
#define SA_BLOCKS 128         // prep: stage-A binning blocks
#define CC_BLOCKS 256         // prep: concat/convert blocks
// tmp packing: col in bits 0..17 (N < 262144), row_local in bits 18..27

typedef __attribute__((ext_vector_type(16))) int int16v;

// ---- prep: stageA binning (blocks 0..127) + concat-fp16 + flag2 zero ----
__global__ void prep(const int* __restrict__ rows, const int* __restrict__ cols,
                     const float* __restrict__ vals, int E,
                     int* __restrict__ gcur, int2* __restrict__ tmp,
                     const float* __restrict__ u, const float* __restrict__ it,
                     long long UD, long long ND, __half* __restrict__ x,
                     int* __restrict__ flag2, int N) {
    __shared__ int hist[256];
    __shared__ int cur[256];
    int t = threadIdx.x;  // blockDim = 1024
    if (blockIdx.x < SA_BLOCKS) {
        if (t < 256) hist[t] = 0;
        __syncthreads();
        int chunk = (E + SA_BLOCKS - 1) / SA_BLOCKS;
        int beg = blockIdx.x * chunk;
        int end = min(beg + chunk, E);
        for (int e = beg + t; e < end; e += 1024)
            atomicAdd(&hist[rows[e] >> CB_SHIFT], 1);
        __syncthreads();
        if (t < 256) {
            int h = hist[t];
            cur[t] = h ? atomicAdd(&gcur[t], h) : 0;
        }
        __syncthreads();
        for (int e = beg + t; e < end; e += 1024) {
            int r = rows[e];
            int cb = r >> CB_SHIFT;
            int p = atomicAdd(&cur[cb], 1);
            tmp[((size_t)cb << CAP_SHIFT) + p] =
                make_int2(cols[e] | ((r & (CB_ROWS - 1)) << 18), __float_as_int(vals[e]));
        }
    } else {
        int lb = blockIdx.x - SA_BLOCKS;
        long long n4 = ND >> 2;
        long long stride = (long long)CC_BLOCKS * 1024;
        for (long long i4 = (long long)lb * 1024 + t; i4 < n4; i4 += stride) {
            long long base = i4 << 2;
            float4 v = (base < UD) ? ((const float4*)u)[i4]
                                   : ((const float4*)it)[(base - UD) >> 2];
            __half2* dst = (__half2*)(x + base);
            dst[0] = __floats2half2_rn(v.x, v.y);
            dst[1] = __floats2half2_rn(v.z, v.w);
        }
        for (long long i = (long long)lb * 1024 + t; i < N; i += stride)
            flag2[i] = 0;
    }
}

// ---- Stage B: per-bucket local count + scan + scatter; emits meta --------
__global__ void stageB(const int* __restrict__ bcnt, int N,
                       const int2* __restrict__ tmp,
                       int2* __restrict__ epack, int2* __restrict__ meta) {
    __shared__ int sc[CB_ROWS];
    __shared__ int cur[CB_ROWS];
    int cb = blockIdx.x;
    int t = threadIdx.x;  // blockDim = CB_ROWS
    size_t base = (size_t)cb << CAP_SHIFT;
    int nb = bcnt[cb];
    sc[t] = 0;
    __syncthreads();
    for (int e = t; e < nb; e += CB_ROWS)
        atomicAdd(&sc[((unsigned)tmp[base + e].x) >> 18], 1);
    __syncthreads();
    int mycnt = sc[t];
    for (int off = 1; off < CB_ROWS; off <<= 1) {
        int v = (t >= off) ? sc[t - off] : 0;
        __syncthreads();
        sc[t] += v;
        __syncthreads();
    }
    int excl = sc[t] - mycnt;
    cur[t] = excl;
    int r = (cb << CB_SHIFT) + t;
    if (r < N) meta[r] = make_int2((int)base + excl, mycnt);
    __syncthreads();
    for (int e = t; e < nb; e += CB_ROWS) {
        int2 pk = tmp[base + e];
        int rl = ((unsigned)pk.x) >> 18;
        int p = atomicAdd(&cur[rl], 1);
        epack[base + p] = make_int2(pk.x & ((1 << 18) - 1), pk.y);
    }
}

// ---- SpMM core: TWO rows per wave, phase-separated for MLP ---------------
// Per 8-edge chunk-pair: both s_load_dwordx16 issue together (one lgkm wait),
// then ALL 16 gathers issue into distinct registers (load phase), then two
// independent FMA chains (compute phase). Dead slots: col sanitized to 0
// (L1-hot row 0) and the ADDEND masked, so garbage/NaN can never enter acc.
__device__ __forceinline__ void pair_dot(const int2* __restrict__ ep,
                                         int begA, int cntA, int begB, int cntB,
                                         const __half* __restrict__ x, int lane,
                                         float& accA_o, float& accB_o) {
    float accA = 0.f, accB = 0.f;
    int mx = max(cntA, cntB);
    for (int e = 0; e < mx; e += 8) {
        int16v edA, edB;
        asm volatile("s_load_dwordx16 %0, %2, 0x0\n\t"
                     "s_load_dwordx16 %1, %3, 0x0\n\t"
                     "s_waitcnt lgkmcnt(0)"
                     : "=s"(edA), "=s"(edB)
                     : "s"(ep + begA + e), "s"(ep + begB + e));
        int remA = cntA - e, remB = cntB - e;
        float xa[8], xb[8];
#pragma unroll
        for (int k = 0; k < 8; ++k) {
            int colA = (k < remA) ? edA[2 * k] : 0;
            int colB = (k < remB) ? edB[2 * k] : 0;
            xa[k] = __half2float(x[((size_t)(unsigned)colA << 6) + lane]);
            xb[k] = __half2float(x[((size_t)(unsigned)colB << 6) + lane]);
        }
#pragma unroll
        for (int k = 0; k < 8; ++k) {
            accA += (k < remA) ? __int_as_float(edA[2 * k + 1]) * xa[k] : 0.f;
            accB += (k < remB) ? __int_as_float(edB[2 * k + 1]) * xb[k] : 0.f;
        }
    }
    accA_o = accA;
    accB_o = accB;
}

// Layer 0: x0 = A @ xcat, rows (2w, 2w+1) per wave. Block 0 zeroes ego1
// row 0 (tmp-alias garbage guard for dead tail gathers downstream).
__global__ void spmm_l0(const int2* __restrict__ meta, const int2* __restrict__ epack,
                        const __half* __restrict__ xcat, int N, __half* __restrict__ y,
                        __half* __restrict__ ego1_row0) {
    int lane = threadIdx.x & 63;
    if (blockIdx.x == 0 && threadIdx.x < D)
        ego1_row0[threadIdx.x] = __float2half(0.0f);
    int w = blockIdx.x * 4 + (threadIdx.x >> 6);
    int rA = 2 * w;
    if (rA >= N) return;   // N even -> rB = rA+1 < N whenever rA < N
    rA = __builtin_amdgcn_readfirstlane(rA);
    int rB = rA + 1;
    int2 mA = meta[rA];
    int2 mB = meta[rB];
    int begA = __builtin_amdgcn_readfirstlane(mA.x);
    int cntA = __builtin_amdgcn_readfirstlane(mA.y);
    int begB = __builtin_amdgcn_readfirstlane(mB.x);
    int cntB = __builtin_amdgcn_readfirstlane(mB.y);
    float accA, accB;
    pair_dot(epack, begA, cntA, begB, cntB, xcat, lane, accA, accB);
    y[((size_t)rA << 6) + lane] = __float2half(accA);
    y[((size_t)rB << 6) + lane] = __float2half(accB);
}

// flag2[c] = 1 for every column c in the edge lists of the 2B output rows
__global__ void mark_flag2(const int* __restrict__ users, const int* __restrict__ items,
                           int B, int U, const int2* __restrict__ meta,
                           const int2* __restrict__ epack, int* __restrict__ flag2) {
    int lane = threadIdx.x & 63;
    int w = blockIdx.x * (blockDim.x >> 6) + (threadIdx.x >> 6);
    if (w >= 2 * B) return;
    int r = (w < B) ? users[w] : U + items[w - B];
    int2 m = meta[r];
    for (int e = m.x + lane; e < m.x + m.y; e += 64)
        flag2[epack[e].x] = 1;
}

// Layer 1 at flagged rows: ego1 = BETA*(A@x0) + ALPHA*x0, row pairs
__global__ void spmm_l1(const int2* __restrict__ meta, const int2* __restrict__ epack,
                        const __half* __restrict__ x0, const int* __restrict__ flag2,
                        int N, __half* __restrict__ y) {
    int lane = threadIdx.x & 63;
    int w = blockIdx.x * 4 + (threadIdx.x >> 6);
    int rA = 2 * w;
    if (rA >= N) return;
    rA = __builtin_amdgcn_readfirstlane(rA);
    int rB = rA + 1;
    int fA = __builtin_amdgcn_readfirstlane(flag2[rA]);
    int fB = __builtin_amdgcn_readfirstlane(flag2[rB]);
    if (!(fA | fB)) return;
    int2 mA = meta[rA];
    int2 mB = meta[rB];
    int begA = __builtin_amdgcn_readfirstlane(mA.x);
    int cntA = fA ? __builtin_amdgcn_readfirstlane(mA.y) : 0;
    int begB = __builtin_amdgcn_readfirstlane(mB.x);
    int cntB = fB ? __builtin_amdgcn_readfirstlane(mB.y) : 0;
    float accA, accB;
    pair_dot(epack, begA, cntA, begB, cntB, x0, lane, accA, accB);
    if (fA) {
        float x0v = __half2float(x0[((size_t)rA << 6) + lane]);
        y[((size_t)rA << 6) + lane] = __float2half(BETA * accA + ALPHA * x0v);
    }
    if (fB) {
        float x0v = __half2float(x0[((size_t)rB << 6) + lane]);
        y[((size_t)rB << 6) + lane] = __float2half(BETA * accB + ALPHA * x0v);
    }
}

// Layer 2 only at the 2B output slots (pairs), fp32 out
__global__ void out_slots(const int* __restrict__ users, const int* __restrict__ items,
                          int B, int U,
                          const int2* __restrict__ meta, const int2* __restrict__ epack,
                          const __half* __restrict__ ego1, const __half* __restrict__ x0,
                          float inv_gamma, float* __restrict__ out) {
    int lane = threadIdx.x & 63;
    int w = blockIdx.x * 4 + (threadIdx.x >> 6);
    int sA = 2 * w;
    if (sA >= 2 * B) return;  // 2B even -> sB < 2B
    int sB = sA + 1;
    int rA = (sA < B) ? users[sA] : U + items[sA - B];
    int rB = (sB < B) ? users[sB] : U + items[sB - B];
    rA = __builtin_amdgcn_readfirstlane(rA);
    rB = __builtin_amdgcn_readfirstlane(rB);
    int2 mA = meta[rA];
    int2 mB = meta[rB];
    int begA = __builtin_amdgcn_readfirstlane(mA.x);
    int cntA = __builtin_amdgcn_readfirstlane(mA.y);
    int begB = __builtin_amdgcn_readfirstlane(mB.x);
    int cntB = __builtin_amdgcn_readfirstlane(mB.y);
    float accA, accB;
    pair_dot(epack, begA, cntA, begB, cntB, ego1, lane, accA, accB);
    float xA = __half2float(x0[((size_t)rA << 6) + lane]);
    float xB = __half2float(x0[((size_t)rB << 6) + lane]);
    out[((size_t)sA << 6) + lane] = (BETA * accA + ALPHA * xA) * inv_gamma;
    out[((size_t)sB << 6) + lane] = (BETA * accB + ALPHA * xB) * inv_gamma;
}

extern "C" void kernel_launch(void* const* d_in, const int* in_sizes, int n_in,
                              void* d_out, int out_size, void* d_ws, size_t ws_size,
                              hipStream_t stream) {
    const int*   users = (const int*)d_in[0];
    const int*   items = (const int*)d_in[1];
    const float* uemb  = (const float*)d_in[2];
    const float* iemb  = (const float*)d_in[3];
    const int*   arows = (const int*)d_in[4];
    const int*   acols = (const int*)d_in[5];
    const float* avals = (const float*)d_in[6];

    const int B = in_sizes[0];
    const int U = in_sizes[2] / D;
    const int I = in_sizes[3] / D;
    const int N = U + I;
    const int E = in_sizes[4];

    const double gamma_d = (double)BETA * BETA * BETA +
                           (double)ALPHA * (1.0 + (double)BETA + (double)BETA * BETA);
    const float inv_gamma = (float)(1.0 / gamma_d);

    const int NCB = (N + CB_ROWS - 1) / CB_ROWS;   // 196 (must be <= 256)

    // Workspace (~105 MB). tmp (slack-bucket staging, 25.7MB) aliases
    // ego1 (25.6MB) + head of x0: tmp dead after stageB; spmm_l0 rewrites all
    // of x0 afterward; ego1 is written at flagged rows (the only rows
    // out_slots gathers) and row 0 is zeroed in spmm_l0 (tail-gather guard).
    char* ws = (char*)d_ws;
    auto align256 = [](size_t x) { return (x + 255) & ~(size_t)255; };
    const size_t ndh_bytes = (size_t)N * D * sizeof(__half);
    const size_t cap_bytes = ((size_t)NCB << CAP_SHIFT) * sizeof(int2) + 512; // + s_load pad
    __half* ego1   = (__half*)ws; ws += align256(ndh_bytes);
    int2*   tmp    = (int2*)ego1;
    __half* x0     = (__half*)ws; ws += align256(ndh_bytes);
    __half* xcat   = (__half*)ws; ws += align256(ndh_bytes);
    int2*  epack   = (int2*)ws;  ws += align256(cap_bytes);
    int2*  meta    = (int2*)ws;  ws += align256((size_t)N * sizeof(int2));
    int*   flag2   = (int*)ws;   ws += align256((size_t)N * sizeof(int));
    int*   gcur    = (int*)ws;   ws += align256(256 * sizeof(int));

    const int threads = 256;
    // row-pair kernels: 4 waves/block, 2 rows/wave -> 8 rows/block
    const int pair_grid = (N / 2 + 3) / 4;
    const int slot_pair_grid = (2 * B / 2 + 3) / 4;
    const int slot_grid = (2 * B + 3) / 4;

    // ---- build: prep (binning ∥ concat ∥ flag2 zero) -> stageB ----
    hipMemsetAsync(gcur, 0, 256 * sizeof(int), stream);
    prep<<<SA_BLOCKS + CC_BLOCKS, 1024, 0, stream>>>(arows, acols, avals, E, gcur, tmp,
                                                     uemb, iemb, (long long)U * D,
                                                     (long long)N * D, xcat, flag2, N);
    stageB<<<NCB, CB_ROWS, 0, stream>>>(gcur, N, tmp, epack, meta);

    // ---- propagation ----
    mark_flag2<<<slot_grid, threads, 0, stream>>>(users, items, B, U, meta, epack, flag2);
    spmm_l0<<<pair_grid, threads, 0, stream>>>(meta, epack, xcat, N, x0, ego1);
    spmm_l1<<<pair_grid, threads, 0, stream>>>(meta, epack, x0, flag2, N, ego1);
    out_slots<<<slot_pair_grid, threads, 0, stream>>>(users, items, B, U, meta, epack,
                                                      ego1, x0, inv_gamma, (float*)d_out);
}

// Round 11
// 177.720 us; speedup vs baseline: 1.0394x; 1.0394x over previous
//
#include <hip/hip_runtime.h>
#include <hip/hip_fp16.h>

#define D 64
#define BETA 0.9f
#define ALPHA 0.1f
#define CB_SHIFT 10
#define CB_ROWS 1024          // rows per coarse bucket
#define CAP_SHIFT 14
#define CAP (1 << CAP_SHIFT)  // edge slots per bucket (16384 >> ~10.2K mean)
#define SA_BLOCKS 128         // prep: stage-A binning blocks
#define CC_BLOCKS 256         // prep: concat/convert blocks
// tmp packing: col in bits 0..17 (N < 262144), row_local in bits 18..27

// ---- prep: stageA binning (blocks 0..127) + concat-fp16 + flag2 zero ----
__global__ void prep(const int* __restrict__ rows, const int* __restrict__ cols,
                     const float* __restrict__ vals, int E,
                     int* __restrict__ gcur, int2* __restrict__ tmp,
                     const float* __restrict__ u, const float* __restrict__ it,
                     long long UD, long long ND, __half* __restrict__ x,
                     int* __restrict__ flag2, int N) {
    __shared__ int hist[256];
    __shared__ int cur[256];
    int t = threadIdx.x;  // blockDim = 1024
    if (blockIdx.x < SA_BLOCKS) {
        if (t < 256) hist[t] = 0;
        __syncthreads();
        int chunk = (E + SA_BLOCKS - 1) / SA_BLOCKS;
        int beg = blockIdx.x * chunk;
        int end = min(beg + chunk, E);
        for (int e = beg + t; e < end; e += 1024)
            atomicAdd(&hist[rows[e] >> CB_SHIFT], 1);
        __syncthreads();
        if (t < 256) {
            int h = hist[t];
            cur[t] = h ? atomicAdd(&gcur[t], h) : 0;
        }
        __syncthreads();
        for (int e = beg + t; e < end; e += 1024) {
            int r = rows[e];
            int cb = r >> CB_SHIFT;
            int p = atomicAdd(&cur[cb], 1);
            tmp[((size_t)cb << CAP_SHIFT) + p] =
                make_int2(cols[e] | ((r & (CB_ROWS - 1)) << 18), __float_as_int(vals[e]));
        }
    } else {
        int lb = blockIdx.x - SA_BLOCKS;
        long long n4 = ND >> 2;
        long long stride = (long long)CC_BLOCKS * 1024;
        for (long long i4 = (long long)lb * 1024 + t; i4 < n4; i4 += stride) {
            long long base = i4 << 2;
            float4 v = (base < UD) ? ((const float4*)u)[i4]
                                   : ((const float4*)it)[(base - UD) >> 2];
            __half2* dst = (__half2*)(x + base);
            dst[0] = __floats2half2_rn(v.x, v.y);
            dst[1] = __floats2half2_rn(v.z, v.w);
        }
        for (long long i = (long long)lb * 1024 + t; i < N; i += stride)
            flag2[i] = 0;
    }
}

// ---- Stage B: per-bucket local count + scan + scatter; emits meta --------
__global__ void stageB(const int* __restrict__ bcnt, int N,
                       const int2* __restrict__ tmp,
                       int2* __restrict__ epack, int2* __restrict__ meta) {
    __shared__ int sc[CB_ROWS];
    __shared__ int cur[CB_ROWS];
    int cb = blockIdx.x;
    int t = threadIdx.x;  // blockDim = CB_ROWS
    size_t base = (size_t)cb << CAP_SHIFT;
    int nb = bcnt[cb];
    sc[t] = 0;
    __syncthreads();
    for (int e = t; e < nb; e += CB_ROWS)
        atomicAdd(&sc[((unsigned)tmp[base + e].x) >> 18], 1);
    __syncthreads();
    int mycnt = sc[t];
    for (int off = 1; off < CB_ROWS; off <<= 1) {
        int v = (t >= off) ? sc[t - off] : 0;
        __syncthreads();
        sc[t] += v;
        __syncthreads();
    }
    int excl = sc[t] - mycnt;
    cur[t] = excl;
    int r = (cb << CB_SHIFT) + t;
    if (r < N) meta[r] = make_int2((int)base + excl, mycnt);
    __syncthreads();
    for (int e = t; e < nb; e += CB_ROWS) {
        int2 pk = tmp[base + e];
        int rl = ((unsigned)pk.x) >> 18;
        int p = atomicAdd(&cur[rl], 1);
        epack[base + p] = make_int2(pk.x & ((1 << 18) - 1), pk.y);
    }
}

// ---- SpMM core: one wave per row; 4 edges per gather instruction ---------
// lane = (g, f): g = lane>>4 selects edge slot, f = lane&15 selects the
// 8-byte feature quad. One gather instr = 64 lanes x 8B = 4 full 128B rows
// (8 cache lines in flight per instr). Edge (col,val) comes via a broadcast
// vector load (16-lane groups share the address) - lands pre-routed per lane.
// Tail: col/val sanitized by (g < rem); val=0 * finite x[row 0] adds 0.
__device__ __forceinline__ void row_accum(const int2* __restrict__ ep,
                                          int beg, int cnt,
                                          const __half* __restrict__ x,
                                          int g, int foff,
                                          float4& A0o, float4& A1o) {
    const char* xb = (const char*)x;
    float4 A0 = {0.f, 0.f, 0.f, 0.f}, A1 = {0.f, 0.f, 0.f, 0.f};
    int full = cnt & ~7;
    int e = 0;
    for (; e < full; e += 8) {
        int2 m0 = ep[beg + e + g];
        int2 m1 = ep[beg + e + 4 + g];
        uint2 q0 = *(const uint2*)(xb + (((size_t)(unsigned)m0.x) << 7) + foff);
        uint2 q1 = *(const uint2*)(xb + (((size_t)(unsigned)m1.x) << 7) + foff);
        float v0 = __int_as_float(m0.y), v1 = __int_as_float(m1.y);
        float2 a = __half22float2(*(__half2*)&q0.x);
        float2 b = __half22float2(*(__half2*)&q0.y);
        float2 c = __half22float2(*(__half2*)&q1.x);
        float2 d = __half22float2(*(__half2*)&q1.y);
        A0.x += v0 * a.x; A0.y += v0 * a.y; A0.z += v0 * b.x; A0.w += v0 * b.y;
        A1.x += v1 * c.x; A1.y += v1 * c.y; A1.z += v1 * d.x; A1.w += v1 * d.y;
    }
    int rem = cnt - e;
    if (rem > 0) {
        int2 m0 = ep[beg + e + g];
        int2 m1 = ep[beg + e + 4 + g];
        bool ok0 = g < rem, ok1 = (g + 4) < rem;
        int c0 = ok0 ? m0.x : 0;
        int c1 = ok1 ? m1.x : 0;
        float v0 = ok0 ? __int_as_float(m0.y) : 0.0f;
        float v1 = ok1 ? __int_as_float(m1.y) : 0.0f;
        uint2 q0 = *(const uint2*)(xb + (((size_t)(unsigned)c0) << 7) + foff);
        uint2 q1 = *(const uint2*)(xb + (((size_t)(unsigned)c1) << 7) + foff);
        float2 a = __half22float2(*(__half2*)&q0.x);
        float2 b = __half22float2(*(__half2*)&q0.y);
        float2 c = __half22float2(*(__half2*)&q1.x);
        float2 d = __half22float2(*(__half2*)&q1.y);
        A0.x += v0 * a.x; A0.y += v0 * a.y; A0.z += v0 * b.x; A0.w += v0 * b.y;
        A1.x += v1 * c.x; A1.y += v1 * c.y; A1.z += v1 * d.x; A1.w += v1 * d.y;
    }
    A0o = A0; A1o = A1;
}

__device__ __forceinline__ float4 group_reduce(float4 A0, float4 A1) {
    float4 A;
    A.x = A0.x + A1.x; A.y = A0.y + A1.y; A.z = A0.z + A1.z; A.w = A0.w + A1.w;
    A.x += __shfl_xor(A.x, 16); A.y += __shfl_xor(A.y, 16);
    A.z += __shfl_xor(A.z, 16); A.w += __shfl_xor(A.w, 16);
    A.x += __shfl_xor(A.x, 32); A.y += __shfl_xor(A.y, 32);
    A.z += __shfl_xor(A.z, 32); A.w += __shfl_xor(A.w, 32);
    return A;
}

// Layer 0: x0 = A @ xcat (one row per wave). Block 0 zeroes ego1 row 0
// (tmp-alias garbage guard for dead tail gathers downstream).
__global__ void spmm_l0(const int2* __restrict__ meta, const int2* __restrict__ epack,
                        const __half* __restrict__ xcat, int N, __half* __restrict__ y,
                        __half* __restrict__ ego1_row0) {
    if (blockIdx.x == 0 && threadIdx.x < D)
        ego1_row0[threadIdx.x] = __float2half(0.0f);
    int lane = threadIdx.x & 63;
    int g = lane >> 4, foff = (lane & 15) * 8;
    int r = blockIdx.x * 4 + (threadIdx.x >> 6);
    if (r >= N) return;
    int2 m = meta[r];
    float4 A0, A1;
    row_accum(epack, m.x, m.y, xcat, g, foff, A0, A1);
    float4 A = group_reduce(A0, A1);
    if (lane < 16) {
        __half2 h0 = __floats2half2_rn(A.x, A.y);
        __half2 h1 = __floats2half2_rn(A.z, A.w);
        uint2 st = make_uint2(*(unsigned*)&h0, *(unsigned*)&h1);
        *(uint2*)((char*)y + (((size_t)r) << 7) + foff) = st;
    }
}

// flag2[c] = 1 for every column c in the edge lists of the 2B output rows
__global__ void mark_flag2(const int* __restrict__ users, const int* __restrict__ items,
                           int B, int U, const int2* __restrict__ meta,
                           const int2* __restrict__ epack, int* __restrict__ flag2) {
    int lane = threadIdx.x & 63;
    int w = blockIdx.x * (blockDim.x >> 6) + (threadIdx.x >> 6);
    if (w >= 2 * B) return;
    int r = (w < B) ? users[w] : U + items[w - B];
    int2 m = meta[r];
    for (int e = m.x + lane; e < m.x + m.y; e += 64)
        flag2[epack[e].x] = 1;
}

// Layer 1 at flagged rows: ego1 = BETA*(A@x0) + ALPHA*x0
__global__ void spmm_l1(const int2* __restrict__ meta, const int2* __restrict__ epack,
                        const __half* __restrict__ x0, const int* __restrict__ flag2,
                        int N, __half* __restrict__ y) {
    int lane = threadIdx.x & 63;
    int g = lane >> 4, foff = (lane & 15) * 8;
    int r = blockIdx.x * 4 + (threadIdx.x >> 6);
    if (r >= N) return;
    if (flag2[r] == 0) return;
    int2 m = meta[r];
    float4 A0, A1;
    row_accum(epack, m.x, m.y, x0, g, foff, A0, A1);
    float4 A = group_reduce(A0, A1);
    if (lane < 16) {
        uint2 xq = *(const uint2*)((const char*)x0 + (((size_t)r) << 7) + foff);
        float2 xa = __half22float2(*(__half2*)&xq.x);
        float2 xb = __half22float2(*(__half2*)&xq.y);
        __half2 h0 = __floats2half2_rn(BETA * A.x + ALPHA * xa.x,
                                       BETA * A.y + ALPHA * xa.y);
        __half2 h1 = __floats2half2_rn(BETA * A.z + ALPHA * xb.x,
                                       BETA * A.w + ALPHA * xb.y);
        uint2 st = make_uint2(*(unsigned*)&h0, *(unsigned*)&h1);
        *(uint2*)((char*)y + (((size_t)r) << 7) + foff) = st;
    }
}

// Layer 2 only at the 2B output slots, fp32 out
__global__ void out_slots(const int* __restrict__ users, const int* __restrict__ items,
                          int B, int U,
                          const int2* __restrict__ meta, const int2* __restrict__ epack,
                          const __half* __restrict__ ego1, const __half* __restrict__ x0,
                          float inv_gamma, float* __restrict__ out) {
    int lane = threadIdx.x & 63;
    int g = lane >> 4, foff = (lane & 15) * 8;
    int w = blockIdx.x * 4 + (threadIdx.x >> 6);
    if (w >= 2 * B) return;
    int r = (w < B) ? users[w] : U + items[w - B];
    int2 m = meta[r];
    float4 A0, A1;
    row_accum(epack, m.x, m.y, ego1, g, foff, A0, A1);
    float4 A = group_reduce(A0, A1);
    if (lane < 16) {
        uint2 xq = *(const uint2*)((const char*)x0 + (((size_t)r) << 7) + foff);
        float2 xa = __half22float2(*(__half2*)&xq.x);
        float2 xb = __half22float2(*(__half2*)&xq.y);
        float4 o;
        o.x = (BETA * A.x + ALPHA * xa.x) * inv_gamma;
        o.y = (BETA * A.y + ALPHA * xa.y) * inv_gamma;
        o.z = (BETA * A.z + ALPHA * xb.x) * inv_gamma;
        o.w = (BETA * A.w + ALPHA * xb.y) * inv_gamma;
        *(float4*)((char*)out + (((size_t)w) << 8) + foff * 2) = o;
    }
}

extern "C" void kernel_launch(void* const* d_in, const int* in_sizes, int n_in,
                              void* d_out, int out_size, void* d_ws, size_t ws_size,
                              hipStream_t stream) {
    const int*   users = (const int*)d_in[0];
    const int*   items = (const int*)d_in[1];
    const float* uemb  = (const float*)d_in[2];
    const float* iemb  = (const float*)d_in[3];
    const int*   arows = (const int*)d_in[4];
    const int*   acols = (const int*)d_in[5];
    const float* avals = (const float*)d_in[6];

    const int B = in_sizes[0];
    const int U = in_sizes[2] / D;
    const int I = in_sizes[3] / D;
    const int N = U + I;
    const int E = in_sizes[4];

    const double gamma_d = (double)BETA * BETA * BETA +
                           (double)ALPHA * (1.0 + (double)BETA + (double)BETA * BETA);
    const float inv_gamma = (float)(1.0 / gamma_d);

    const int NCB = (N + CB_ROWS - 1) / CB_ROWS;   // 196 (must be <= 256)

    // Workspace (~105 MB). tmp (slack-bucket staging, 25.7MB) aliases
    // ego1 (25.6MB) + head of x0: tmp dead after stageB; spmm_l0 rewrites all
    // of x0 afterward; ego1 is written at flagged rows (the only rows
    // out_slots gathers) and row 0 is zeroed in spmm_l0 (tail-gather guard).
    char* ws = (char*)d_ws;
    auto align256 = [](size_t x) { return (x + 255) & ~(size_t)255; };
    const size_t ndh_bytes = (size_t)N * D * sizeof(__half);
    const size_t cap_bytes = ((size_t)NCB << CAP_SHIFT) * sizeof(int2) + 512; // + tail pad
    __half* ego1   = (__half*)ws; ws += align256(ndh_bytes);
    int2*   tmp    = (int2*)ego1;
    __half* x0     = (__half*)ws; ws += align256(ndh_bytes);
    __half* xcat   = (__half*)ws; ws += align256(ndh_bytes);
    int2*  epack   = (int2*)ws;  ws += align256(cap_bytes);
    int2*  meta    = (int2*)ws;  ws += align256((size_t)N * sizeof(int2));
    int*   flag2   = (int*)ws;   ws += align256((size_t)N * sizeof(int));
    int*   gcur    = (int*)ws;   ws += align256(256 * sizeof(int));

    const int threads = 256;           // 4 waves/block, 1 row/wave
    const int spmm_grid = (N + 3) / 4;
    const int slot_grid = (2 * B + 3) / 4;

    // ---- build: prep (binning ∥ concat ∥ flag2 zero) -> stageB ----
    hipMemsetAsync(gcur, 0, 256 * sizeof(int), stream);
    prep<<<SA_BLOCKS + CC_BLOCKS, 1024, 0, stream>>>(arows, acols, avals, E, gcur, tmp,
                                                     uemb, iemb, (long long)U * D,
                                                     (long long)N * D, xcat, flag2, N);
    stageB<<<NCB, CB_ROWS, 0, stream>>>(gcur, N, tmp, epack, meta);

    // ---- propagation ----
    mark_flag2<<<slot_grid, threads, 0, stream>>>(users, items, B, U, meta, epack, flag2);
    spmm_l0<<<spmm_grid, threads, 0, stream>>>(meta, epack, xcat, N, x0, ego1);
    spmm_l1<<<spmm_grid, threads, 0, stream>>>(meta, epack, x0, flag2, N, ego1);
    out_slots<<<slot_grid, threads, 0, stream>>>(users, items, B, U, meta, epack,
                                                 ego1, x0, inv_gamma, (float*)d_out);
}

// Round 12
// 166.681 us; speedup vs baseline: 1.1083x; 1.0662x over previous
//
#include <hip/hip_runtime.h>
#include <hip/hip_fp16.h>

#define D 64
#define BETA 0.9f
#define ALPHA 0.1f
#define CB_SHIFT 10
#define CB_ROWS 1024          // rows per coarse bucket
#define CAP_SHIFT 14
#define CAP (1 << CAP_SHIFT)  // slots/bucket: padded mean ~13.8K vs 16.4K (~20 sigma)
#define SA_BLOCKS 128         // prep: stage-A binning blocks
#define CC_BLOCKS 256         // prep: concat/convert blocks
// tmp packing: col in bits 0..17 (N < 262144), row_local in bits 18..27

typedef __attribute__((ext_vector_type(16))) int int16v;

// ---- prep: stageA binning (blocks 0..127) + concat-fp16 + flag2 zero ----
__global__ void prep(const int* __restrict__ rows, const int* __restrict__ cols,
                     const float* __restrict__ vals, int E,
                     int* __restrict__ gcur, int2* __restrict__ tmp,
                     const float* __restrict__ u, const float* __restrict__ it,
                     long long UD, long long ND, __half* __restrict__ x,
                     int* __restrict__ flag2, int N) {
    __shared__ int hist[256];
    __shared__ int cur[256];
    int t = threadIdx.x;  // blockDim = 1024
    if (blockIdx.x < SA_BLOCKS) {
        if (t < 256) hist[t] = 0;
        __syncthreads();
        int chunk = (E + SA_BLOCKS - 1) / SA_BLOCKS;
        int beg = blockIdx.x * chunk;
        int end = min(beg + chunk, E);
        for (int e = beg + t; e < end; e += 1024)
            atomicAdd(&hist[rows[e] >> CB_SHIFT], 1);
        __syncthreads();
        if (t < 256) {
            int h = hist[t];
            cur[t] = h ? atomicAdd(&gcur[t], h) : 0;
        }
        __syncthreads();
        for (int e = beg + t; e < end; e += 1024) {
            int r = rows[e];
            int cb = r >> CB_SHIFT;
            int p = atomicAdd(&cur[cb], 1);
            tmp[((size_t)cb << CAP_SHIFT) + p] =
                make_int2(cols[e] | ((r & (CB_ROWS - 1)) << 18), __float_as_int(vals[e]));
        }
    } else {
        int lb = blockIdx.x - SA_BLOCKS;
        long long n4 = ND >> 2;
        long long stride = (long long)CC_BLOCKS * 1024;
        for (long long i4 = (long long)lb * 1024 + t; i4 < n4; i4 += stride) {
            long long base = i4 << 2;
            float4 v = (base < UD) ? ((const float4*)u)[i4]
                                   : ((const float4*)it)[(base - UD) >> 2];
            __half2* dst = (__half2*)(x + base);
            dst[0] = __floats2half2_rn(v.x, v.y);
            dst[1] = __floats2half2_rn(v.z, v.w);
        }
        for (long long i = (long long)lb * 1024 + t; i < N; i += stride)
            flag2[i] = 0;
    }
}

// ---- Stage B: per-bucket count + PADDED scan + scatter; emits meta -------
// Row starts padded to 8-slot (64B) boundaries -> every s_load_dwordx16 in
// the SpMM kernels is 64B-aligned. Pad slots are sanitized to (0,0) so the
// SpMM hot loop needs NO tail masking (val=0 contributes 0 via finite row 0).
__global__ void stageB(const int* __restrict__ bcnt, int N,
                       const int2* __restrict__ tmp,
                       int2* __restrict__ epack, int2* __restrict__ meta) {
    __shared__ int sc[CB_ROWS];
    __shared__ int cur[CB_ROWS];
    int cb = blockIdx.x;
    int t = threadIdx.x;  // blockDim = CB_ROWS
    size_t base = (size_t)cb << CAP_SHIFT;
    int nb = bcnt[cb];
    sc[t] = 0;
    __syncthreads();
    for (int e = t; e < nb; e += CB_ROWS)
        atomicAdd(&sc[((unsigned)tmp[base + e].x) >> 18], 1);
    __syncthreads();
    int mycnt = sc[t];
    int cnt8 = (mycnt + 7) & ~7;
    __syncthreads();
    sc[t] = cnt8;
    __syncthreads();
    for (int off = 1; off < CB_ROWS; off <<= 1) {
        int v = (t >= off) ? sc[t - off] : 0;
        __syncthreads();
        sc[t] += v;
        __syncthreads();
    }
    int excl8 = sc[t] - cnt8;     // padded exclusive prefix within bucket
    cur[t] = excl8;
    int r = (cb << CB_SHIFT) + t;
    if (r < N) meta[r] = make_int2((int)base + excl8, mycnt);
    for (int k = mycnt; k < cnt8; ++k)            // sanitize pad slots
        epack[base + excl8 + k] = make_int2(0, 0);
    __syncthreads();
    for (int e = t; e < nb; e += CB_ROWS) {
        int2 pk = tmp[base + e];
        int rl = ((unsigned)pk.x) >> 18;
        int p = atomicAdd(&cur[rl], 1);
        epack[base + p] = make_int2(pk.x & ((1 << 18) - 1), pk.y);
    }
}

// ---- SpMM core: scalar edge fetch, aligned, tail-free --------------------
// 8 edges per 64B-aligned s_load_dwordx16; cols/vals stay in SGPRs (saddr
// gather, val = the FMA's one SGPR operand). Pad slots are (0,0): they add
// 0 * x[row 0] (finite) - no masking needed anywhere.
__device__ __forceinline__ float row_dot_s(const int2* __restrict__ ep,
                                           int beg, int cnt,
                                           const __half* __restrict__ x, int lane) {
    float acc = 0.f;
    int cnt8 = (cnt + 7) & ~7;
    for (int e = 0; e < cnt8; e += 8) {
        int16v ed;
        asm volatile("s_load_dwordx16 %0, %1, 0x0\n\ts_waitcnt lgkmcnt(0)"
                     : "=s"(ed)
                     : "s"(ep + beg + e));
#define EDGEF(k)                                                              \
        acc += __int_as_float(ed[2 * (k) + 1]) *                              \
               __half2float(x[((size_t)(unsigned)ed[2 * (k)] << 6) + lane]);
        EDGEF(0) EDGEF(1) EDGEF(2) EDGEF(3) EDGEF(4) EDGEF(5) EDGEF(6) EDGEF(7)
#undef EDGEF
    }
    return acc;
}

// Layer 0: x0 = A @ xcat (blocks < spmm_blocks); tail blocks mark flag2.
// Block 0 also zeroes ego1 row 0 (tmp-alias garbage guard: pad-slot gathers
// in out_slots read ego1 row 0).
__global__ void spmm_l0(const int2* __restrict__ meta, const int2* __restrict__ epack,
                        const __half* __restrict__ xcat, int N, __half* __restrict__ y,
                        __half* __restrict__ ego1_row0,
                        const int* __restrict__ users, const int* __restrict__ items,
                        int B, int U, int* __restrict__ flag2, int spmm_blocks) {
    int lane = threadIdx.x & 63;
    int wv = threadIdx.x >> 6;
    if (blockIdx.x >= spmm_blocks) {
        int w = (blockIdx.x - spmm_blocks) * 4 + wv;
        if (w >= 2 * B) return;
        int r = (w < B) ? users[w] : U + items[w - B];
        int2 m = meta[r];
        for (int e = m.x + lane; e < m.x + m.y; e += 64)
            flag2[epack[e].x] = 1;
        return;
    }
    if (blockIdx.x == 0 && threadIdx.x < D)
        ego1_row0[threadIdx.x] = __float2half(0.0f);
    int r = blockIdx.x * 4 + wv;
    if (r >= N) return;
    r = __builtin_amdgcn_readfirstlane(r);
    int2 m = meta[r];
    int beg = __builtin_amdgcn_readfirstlane(m.x);
    int cnt = __builtin_amdgcn_readfirstlane(m.y);
    float acc = row_dot_s(epack, beg, cnt, xcat, lane);
    y[((size_t)r << 6) + lane] = __float2half(acc);
}

// Layer 1 at flagged rows: ego1 = BETA*(A@x0) + ALPHA*x0
__global__ void spmm_l1(const int2* __restrict__ meta, const int2* __restrict__ epack,
                        const __half* __restrict__ x0, const int* __restrict__ flag2,
                        int N, __half* __restrict__ y) {
    int lane = threadIdx.x & 63;
    int r = blockIdx.x * (blockDim.x >> 6) + (threadIdx.x >> 6);
    if (r >= N) return;
    r = __builtin_amdgcn_readfirstlane(r);
    if (flag2[r] == 0) return;
    int2 m = meta[r];
    int beg = __builtin_amdgcn_readfirstlane(m.x);
    int cnt = __builtin_amdgcn_readfirstlane(m.y);
    float acc = row_dot_s(epack, beg, cnt, x0, lane);
    float x0v = __half2float(x0[((size_t)r << 6) + lane]);
    y[((size_t)r << 6) + lane] = __float2half(BETA * acc + ALPHA * x0v);
}

// Layer 2 only at the 2B output slots, fp32 out
__global__ void out_slots(const int* __restrict__ users, const int* __restrict__ items,
                          int B, int U,
                          const int2* __restrict__ meta, const int2* __restrict__ epack,
                          const __half* __restrict__ ego1, const __half* __restrict__ x0,
                          float inv_gamma, float* __restrict__ out) {
    int lane = threadIdx.x & 63;
    int w = blockIdx.x * (blockDim.x >> 6) + (threadIdx.x >> 6);
    if (w >= 2 * B) return;
    int r = (w < B) ? users[w] : U + items[w - B];
    r = __builtin_amdgcn_readfirstlane(r);
    int2 m = meta[r];
    int beg = __builtin_amdgcn_readfirstlane(m.x);
    int cnt = __builtin_amdgcn_readfirstlane(m.y);
    float acc = row_dot_s(epack, beg, cnt, ego1, lane);
    float x0v = __half2float(x0[((size_t)r << 6) + lane]);
    out[((size_t)w << 6) + lane] = (BETA * acc + ALPHA * x0v) * inv_gamma;
}

extern "C" void kernel_launch(void* const* d_in, const int* in_sizes, int n_in,
                              void* d_out, int out_size, void* d_ws, size_t ws_size,
                              hipStream_t stream) {
    const int*   users = (const int*)d_in[0];
    const int*   items = (const int*)d_in[1];
    const float* uemb  = (const float*)d_in[2];
    const float* iemb  = (const float*)d_in[3];
    const int*   arows = (const int*)d_in[4];
    const int*   acols = (const int*)d_in[5];
    const float* avals = (const float*)d_in[6];

    const int B = in_sizes[0];
    const int U = in_sizes[2] / D;
    const int I = in_sizes[3] / D;
    const int N = U + I;
    const int E = in_sizes[4];

    const double gamma_d = (double)BETA * BETA * BETA +
                           (double)ALPHA * (1.0 + (double)BETA + (double)BETA * BETA);
    const float inv_gamma = (float)(1.0 / gamma_d);

    const int NCB = (N + CB_ROWS - 1) / CB_ROWS;   // 196 (must be <= 256)

    // Workspace (~105 MB). tmp (slack-bucket staging, 25.7MB) aliases
    // ego1 (25.6MB) + head of x0: tmp dead after stageB; spmm_l0 rewrites all
    // of x0 afterward; ego1 is written at flagged rows (the only rows
    // out_slots gathers) and row 0 is zeroed in spmm_l0 (pad-gather guard).
    char* ws = (char*)d_ws;
    auto align256 = [](size_t x) { return (x + 255) & ~(size_t)255; };
    const size_t ndh_bytes = (size_t)N * D * sizeof(__half);
    const size_t cap_bytes = ((size_t)NCB << CAP_SHIFT) * sizeof(int2) + 512; // + pad
    __half* ego1   = (__half*)ws; ws += align256(ndh_bytes);
    int2*   tmp    = (int2*)ego1;
    __half* x0     = (__half*)ws; ws += align256(ndh_bytes);
    __half* xcat   = (__half*)ws; ws += align256(ndh_bytes);
    int2*  epack   = (int2*)ws;  ws += align256(cap_bytes);
    int2*  meta    = (int2*)ws;  ws += align256((size_t)N * sizeof(int2));
    int*   flag2   = (int*)ws;   ws += align256((size_t)N * sizeof(int));
    int*   gcur    = (int*)ws;   ws += align256(256 * sizeof(int));

    const int threads = 256;
    const int rows_per_block = threads / 64;
    const int spmm_grid = (N + rows_per_block - 1) / rows_per_block;
    const int slot_grid = (2 * B + rows_per_block - 1) / rows_per_block;

    // ---- build: prep (binning ∥ concat ∥ flag2 zero) -> stageB ----
    hipMemsetAsync(gcur, 0, 256 * sizeof(int), stream);
    prep<<<SA_BLOCKS + CC_BLOCKS, 1024, 0, stream>>>(arows, acols, avals, E, gcur, tmp,
                                                     uemb, iemb, (long long)U * D,
                                                     (long long)N * D, xcat, flag2, N);
    stageB<<<NCB, CB_ROWS, 0, stream>>>(gcur, N, tmp, epack, meta);

    // ---- propagation (l0 + flag-marking fused in one dispatch) ----
    spmm_l0<<<spmm_grid + slot_grid, threads, 0, stream>>>(meta, epack, xcat, N, x0, ego1,
                                                           users, items, B, U, flag2,
                                                           spmm_grid);
    spmm_l1<<<spmm_grid, threads, 0, stream>>>(meta, epack, x0, flag2, N, ego1);
    out_slots<<<slot_grid, threads, 0, stream>>>(users, items, B, U, meta, epack,
                                                 ego1, x0, inv_gamma, (float*)d_out);
}